// Round 4
// baseline (170.013 us; speedup 1.0000x reference)
//
#include <hip/hip_runtime.h>
#include <math.h>

#define NB 8
#define S 2048
#define D 128
#define ROWS 32          // q-rows per block
#define CAP 64           // candidate capacity per row (== wave size for ballot compaction)
#define NTH 256
#define WKEYS 512        // keys per wave
#define CHUNK 32         // keys per chunk
#define NCK (WKEYS / CHUNK)   // 16
#define MARGIN 1.6f      // 1.0 support lemma + 0.6 bf16 screening error bound

typedef __attribute__((ext_vector_type(8))) short bf16x8;
typedef __attribute__((ext_vector_type(4))) float f32x4;

__device__ __forceinline__ unsigned fmap(float f) {
    unsigned u = __float_as_uint(f);
    return (u & 0x80000000u) ? ~u : (u | 0x80000000u);
}
__device__ __forceinline__ float funmap(unsigned k) {
    return (k & 0x80000000u) ? __uint_as_float(k ^ 0x80000000u) : __uint_as_float(~k);
}
// RNE fp32->bf16, pure integer ops (proven in R2's convert_kernel)
__device__ __forceinline__ unsigned short f2bf(float f) {
    unsigned u = __float_as_uint(f);
    return (unsigned short)((u + 0x7fffu + ((u >> 16) & 1u)) >> 16);
}
// 8 floats -> one bf16x8 MFMA fragment word
__device__ __forceinline__ bf16x8 pack8(const float4 a, const float4 b, const float sc) {
    bf16x8 r;
    r[0] = (short)f2bf(sc * a.x);
    r[1] = (short)f2bf(sc * a.y);
    r[2] = (short)f2bf(sc * a.z);
    r[3] = (short)f2bf(sc * a.w);
    r[4] = (short)f2bf(sc * b.x);
    r[5] = (short)f2bf(sc * b.y);
    r[6] = (short)f2bf(sc * b.z);
    r[7] = (short)f2bf(sc * b.w);
    return r;
}

// Single fused kernel: bf16-MFMA screening + exact fp32 rescore + closed-form
// entmax-1.5 + sparse PV. Algorithm identical to the R2-proven two-kernel
// version; the fp32->bf16 conversion now happens in-register (f2bf) instead
// of a separate convert kernel + workspace.
__global__ __launch_bounds__(NTH, 2) void entmax_fused2_kernel(
    const float* __restrict__ query, const float* __restrict__ key,
    const float* __restrict__ value, float* __restrict__ out)
{
    __shared__ float cVal[ROWS][CAP];            // 8 KB
    __shared__ unsigned short cIdx[ROWS][CAP];   // 4 KB
    __shared__ unsigned rmS[ROWS];
    __shared__ int ccnt[ROWS];

    const int tid  = threadIdx.x;
    const int b    = blockIdx.x & 7;             // batch -> XCD (perf heuristic only)
    const int rb   = blockIdx.x >> 3;            // row-block within batch
    const int w    = tid >> 6;                   // wave 0..3
    const int lane = tid & 63;
    const int g    = lane >> 4;                  // k-group for MFMA frags
    const int l15  = lane & 15;

    if (tid < ROWS) { rmS[tid] = fmap(-3.0e38f); ccnt[tid] = 0; }
    __syncthreads();

    const float4* QF4 = (const float4*)(query + (size_t)(b * S + rb * ROWS) * D);
    const float4* KF4 = (const float4*)(key + (size_t)b * S * D);

    // A-frags: Q' = bf16(0.5*q), all held in registers for the whole kernel.
    // Lane (g,l15): Q row (rt*16+l15), k-elems s*32+g*8 .. +8  (identical to R2's layout)
    bf16x8 aq[2][4];
    #pragma unroll
    for (int rt = 0; rt < 2; rt++)
        #pragma unroll
        for (int s = 0; s < 4; s++) {
            const float4* P = QF4 + (rt * 16 + l15) * 32 + s * 8 + g * 2;
            aq[rt][s] = pack8(P[0], P[1], 0.5f);
        }

    const int key0w = w * WKEYS;

    float rmr[2][4];                              // per-wave running row max (bf16 scores)
    #pragma unroll
    for (int rt = 0; rt < 2; rt++)
        #pragma unroll
        for (int j = 0; j < 4; j++) rmr[rt][j] = -3.0e38f;

    float4 raw0[16], raw1[16];   // raw fp32 staging, [kt*8 + s*2 + h]

// Load one 32-key chunk's raw fp32 fragments. Lane (g,l15): key row
// (base + kt*16 + l15), float elems s*32+g*8 .. +8  => 2 float4 per (kt,s).
#define LOADB(dst, ck_)                                                              \
    {                                                                                \
        _Pragma("unroll")                                                            \
        for (int kt = 0; kt < 2; kt++)                                               \
            _Pragma("unroll")                                                        \
            for (int s = 0; s < 4; s++) {                                            \
                const float4* P_ = KF4 +                                             \
                    (size_t)(key0w + (ck_) * CHUNK + kt * 16 + l15) * 32 + s * 8 + g * 2; \
                dst[kt * 8 + s * 2 + 0] = P_[0];                                     \
                dst[kt * 8 + s * 2 + 1] = P_[1];                                     \
            }                                                                        \
    }

#define CHUNK_BODY(cur, nxt, ck_)                                                    \
    {                                                                                \
        /* convert staged raw fp32 -> bf16 fragments (frees cur for reload) */       \
        bf16x8 fb[2][4];                                                             \
        _Pragma("unroll")                                                            \
        for (int kt = 0; kt < 2; kt++)                                               \
            _Pragma("unroll")                                                        \
            for (int s = 0; s < 4; s++)                                              \
                fb[kt][s] = pack8(cur[kt * 8 + s * 2], cur[kt * 8 + s * 2 + 1], 1.0f); \
        if ((ck_) + 1 < NCK) LOADB(nxt, (ck_) + 1);                                  \
        f32x4 acc[2][2];                                                             \
        _Pragma("unroll")                                                            \
        for (int rt = 0; rt < 2; rt++)                                               \
            _Pragma("unroll")                                                        \
            for (int kt = 0; kt < 2; kt++) acc[rt][kt] = (f32x4){0.f, 0.f, 0.f, 0.f}; \
        _Pragma("unroll")                                                            \
        for (int s = 0; s < 4; s++) {                                                \
            _Pragma("unroll")                                                        \
            for (int rt = 0; rt < 2; rt++) {                                         \
                acc[rt][0] = __builtin_amdgcn_mfma_f32_16x16x32_bf16(aq[rt][s], fb[0][s], acc[rt][0], 0, 0, 0); \
                acc[rt][1] = __builtin_amdgcn_mfma_f32_16x16x32_bf16(aq[rt][s], fb[1][s], acc[rt][1], 0, 0, 0); \
            }                                                                        \
        }                                                                            \
        /* C layout (m89-verified, R2-validated): row = rt*16+g*4+j, key-col = kt*16+l15 */ \
        float red[2][4];                                                             \
        _Pragma("unroll")                                                            \
        for (int rt = 0; rt < 2; rt++)                                               \
            _Pragma("unroll")                                                        \
            for (int j = 0; j < 4; j++) red[rt][j] = fmaxf(acc[rt][0][j], acc[rt][1][j]); \
        _Pragma("unroll")                                                            \
        for (int m = 1; m <= 8; m <<= 1)                                             \
            _Pragma("unroll")                                                        \
            for (int rt = 0; rt < 2; rt++)                                           \
                _Pragma("unroll")                                                    \
                for (int j = 0; j < 4; j++)                                          \
                    red[rt][j] = fmaxf(red[rt][j], __shfl_xor(red[rt][j], m));       \
        bool up[2][4];                                                               \
        _Pragma("unroll")                                                            \
        for (int rt = 0; rt < 2; rt++)                                               \
            _Pragma("unroll")                                                        \
            for (int j = 0; j < 4; j++) {                                            \
                up[rt][j] = red[rt][j] > rmr[rt][j];                                 \
                rmr[rt][j] = fmaxf(rmr[rt][j], red[rt][j]);                          \
            }                                                                        \
        if (l15 == 0) {                                                              \
            _Pragma("unroll")                                                        \
            for (int rt = 0; rt < 2; rt++)                                           \
                _Pragma("unroll")                                                    \
                for (int j = 0; j < 4; j++)                                          \
                    if (up[rt][j]) atomicMax(&rmS[rt * 16 + g * 4 + j], fmap(rmr[rt][j])); \
        }                                                                            \
        float thr[2][4];                                                             \
        _Pragma("unroll")                                                            \
        for (int rt = 0; rt < 2; rt++)                                               \
            _Pragma("unroll")                                                        \
            for (int j = 0; j < 4; j++)                                              \
                thr[rt][j] = fmaxf(rmr[rt][j], funmap(rmS[rt * 16 + g * 4 + j])) - MARGIN; \
        int kb0_ = key0w + (ck_) * CHUNK + l15;                                      \
        _Pragma("unroll")                                                            \
        for (int rt = 0; rt < 2; rt++)                                               \
            _Pragma("unroll")                                                        \
            for (int kt = 0; kt < 2; kt++)                                           \
                _Pragma("unroll")                                                    \
                for (int j = 0; j < 4; j++) {                                        \
                    float v_ = acc[rt][kt][j];                                       \
                    if (v_ > thr[rt][j]) {                                           \
                        int row_ = rt * 16 + g * 4 + j;                              \
                        int slot_ = atomicAdd(&ccnt[row_], 1);                       \
                        if (slot_ < CAP) {                                           \
                            cVal[row_][slot_] = v_;                                  \
                            cIdx[row_][slot_] = (unsigned short)(kb0_ + kt * 16);    \
                        }                                                            \
                    }                                                                \
                }                                                                    \
    }

    LOADB(raw0, 0);
    for (int t = 0; t < NCK / 2; t++) {
        CHUNK_BODY(raw0, raw1, 2 * t);
        CHUNK_BODY(raw1, raw0, 2 * t + 1);
    }

    // final cross-wave max merge
    if (l15 == 0) {
        #pragma unroll
        for (int rt = 0; rt < 2; rt++)
            #pragma unroll
            for (int j = 0; j < 4; j++)
                atomicMax(&rmS[rt * 16 + g * 4 + j], fmap(rmr[rt][j]));
    }
    __syncthreads();

    // ---------------- epilogue (R2-verbatim): wave w owns rows w*8 .. w*8+7 ----------------
    const float* Qg = query + (size_t)(b * S + rb * ROWS) * D;
    const float* Kg = key   + (size_t)b * S * D;
    const float* Vg = value + (size_t)b * S * D;
    float* Og = out + (size_t)(b * S + rb * ROWS) * D;

    for (int r8 = 0; r8 < 8; r8++) {
        int row = w * 8 + r8;
        int n = min(ccnt[row], CAP);
        float thrc = funmap(rmS[row]) - MARGIN;

        // wave-parallel compaction against the FINAL bf16 max (lane == slot, CAP == 64)
        float v = (lane < n) ? cVal[row][lane] : -3.0e38f;
        unsigned short id = (lane < n) ? cIdx[row][lane] : 0;
        unsigned long long mk = __ballot(v > thrc);
        int nc = __popcll(mk);
        int pos = __popcll(mk & ((1ull << lane) - 1ull));
        if (v > thrc) cIdx[row][pos] = id;   // reads already in regs; wave-lockstep safe

        // exact fp32 rescore: 8 lanes per candidate, 16 d-elems per lane
        int c0 = lane >> 3;
        int dl = lane & 7;
        float4 q4[4];
        #pragma unroll
        for (int i = 0; i < 4; i++)
            q4[i] = ((const float4*)(Qg + (size_t)row * D))[dl * 4 + i];
        for (int cc = c0; cc < nc; cc += 8) {
            int ky = cIdx[row][cc];
            float s = 0.f;
            #pragma unroll
            for (int i = 0; i < 4; i++) {
                float4 k4 = ((const float4*)(Kg + (size_t)ky * D))[dl * 4 + i];
                s = fmaf(q4[i].x, k4.x, s);
                s = fmaf(q4[i].y, k4.y, s);
                s = fmaf(q4[i].z, k4.z, s);
                s = fmaf(q4[i].w, k4.w, s);
            }
            s += __shfl_xor(s, 1);
            s += __shfl_xor(s, 2);
            s += __shfl_xor(s, 4);
            if (dl == 0) cVal[row][cc] = 0.5f * s;   // x = (alpha-1) * z, exact fp32
        }

        // closed-form entmax-1.5 threshold (lane 0): sort desc,
        // tau_k = (S1 - sqrt(S1^2 - k(S2-1)))/k over sorted prefix
        float tauf = 0.f;
        if (lane == 0) {
            for (int i = 0; i < nc - 1; i++) {            // selection sort (nc tiny)
                int mi = i; float mv = cVal[row][i];
                for (int j2 = i + 1; j2 < nc; j2++)
                    if (cVal[row][j2] > mv) { mv = cVal[row][j2]; mi = j2; }
                if (mi != i) {
                    float tv = cVal[row][i]; cVal[row][i] = cVal[row][mi]; cVal[row][mi] = tv;
                    unsigned short ti = cIdx[row][i]; cIdx[row][i] = cIdx[row][mi]; cIdx[row][mi] = ti;
                }
            }
            double S1 = 0.0, S2 = 0.0;
            double tau = (double)cVal[row][0] - 1.0;      // k=1 solution (always valid)
            for (int k2 = 1; k2 <= nc; k2++) {
                double xk = (double)cVal[row][k2 - 1];
                S1 += xk; S2 += xk * xk;
                double disc = S1 * S1 - (double)k2 * (S2 - 1.0);
                if (disc >= 0.0) {
                    double tk = (S1 - sqrt(disc)) / (double)k2;
                    if (xk > tk) tau = tk;                // keep largest valid k
                }
            }
            tauf = (float)tau;
        }
        tauf = __shfl(tauf, 0);

        // p = max(x - tau, 0)^2, normalize, sparse PV (lanes cover D as float2)
        float Z = 0.f;
        float2 o = make_float2(0.f, 0.f);
        for (int cc = 0; cc < nc; cc++) {
            float x = cVal[row][cc];
            float t = fmaxf(x - tauf, 0.f);
            float p = t * t;
            Z += p;
            if (t > 0.f) {
                int ky = cIdx[row][cc];
                float2 a = ((const float2*)(Vg + (size_t)ky * D))[lane];
                o.x = fmaf(p, a.x, o.x);
                o.y = fmaf(p, a.y, o.y);
            }
        }
        float zi = 1.0f / Z;
        ((float2*)(Og + (size_t)row * D))[lane] = make_float2(o.x * zi, o.y * zi);
    }
}

extern "C" void kernel_launch(void* const* d_in, const int* in_sizes, int n_in,
                              void* d_out, int out_size, void* d_ws, size_t ws_size,
                              hipStream_t stream) {
    const float* q = (const float*)d_in[0];
    const float* k = (const float*)d_in[1];
    const float* v = (const float*)d_in[2];
    float* o = (float*)d_out;
    dim3 grid(NB * (S / ROWS));   // 8 * 64 = 512 blocks
    dim3 block(NTH);
    hipLaunchKernelGGL(entmax_fused2_kernel, grid, block, 0, stream, q, k, v, o);
}